// Round 3
// baseline (12192.625 us; speedup 1.0000x reference)
//
#include <hip/hip_runtime.h>
#include <math.h>
#include <stddef.h>

// ---------------------------------------------------------------------------
// ATT_SYN: bi-LSTM encoder + synopsis attention + 2nd bi-LSTM + tag head.
// B=8 T=512 S=32 J=64 D=400 R=256 MDU=100 TAGS=7
// DTYPE-AGNOSTIC: detect_k probes input_text to decide bf16 vs f32 inputs
// (flag in d_ws); all raw-input readers branch on it. Internals: bf16 MFMA
// GEMMs (fp32 accum), fp32 LSTM recurrence in LDS.
// ---------------------------------------------------------------------------

#define BB 8
#define TT 512
#define SS 32
#define JJ 64
#define DD 400
#define RR 256
#define G4 1024
#define H2 512
#define MDU_ 100
#define TAGS_ 7
#define BT (BB*TT)
#define NSEQ (BB*SS)
#define SCH 64
#define MB1 (1024*1024)

typedef __attribute__((ext_vector_type(8))) short short8;
typedef __attribute__((ext_vector_type(4))) float floatx4;
typedef unsigned short u16;

__device__ __forceinline__ float us2f(u16 u) {
    unsigned int v = ((unsigned int)u) << 16;
    return __builtin_bit_cast(float, v);
}
__device__ __forceinline__ u16 f2us(float f) {
    unsigned int v = __builtin_bit_cast(unsigned int, f);
    v += 0x7FFFu + ((v >> 16) & 1u);
    return (u16)(v >> 16);
}
__device__ __forceinline__ float ldin(const void* p, long i, int bf) {
    return bf ? us2f(((const u16*)p)[i]) : ((const float*)p)[i];
}
__device__ __forceinline__ float sigm(float x) { return 1.0f / (1.0f + expf(-x)); }

// ---- dtype probe: even ushorts are valid ~N(0,1) bf16 iff data is bf16 ----
__global__ void detect_k(const void* x, int* flag) {
    __shared__ int cnt;
    if (threadIdx.x == 0) cnt = 0;
    __syncthreads();
    u16 lo = ((const u16*)x)[threadIdx.x * 2];
    int e = (lo >> 7) & 0xFF;
    if (e >= 118 && e <= 131) atomicAdd(&cnt, 1);
    __syncthreads();
    if (threadIdx.x == 0) *flag = (cnt > 128) ? 1 : 0;
}
// cast raw input -> bf16 copy
__global__ void castbf_k(const void* src, long off, u16* dst, long n, const int* flag) {
    long i = (long)blockIdx.x * 256 + threadIdx.x;
    if (i < n) dst[i] = (*flag) ? ((const u16*)src)[off + i] : f2us(((const float*)src)[off + i]);
}
// cast raw input -> f32 copy
__global__ void castf_k(const void* src, float* dst, long n, const int* flag) {
    long i = (long)blockIdx.x * 256 + threadIdx.x;
    if (i < n) dst[i] = ldin(src, i, *flag);
}
// Whh [4R,R] -> transposed fp32 WhT[k*1024+g]
__global__ void whh_t_k(const void* Whh, float* WhT, const int* flag) {
    int i = blockIdx.x * 256 + threadIdx.x;
    if (i < G4 * RR) {
        int g = i >> 8, k = i & 255;
        WhT[k * G4 + g] = ldin(Whh, i, *flag);
    }
}
__global__ void bias_sum_k(const void* bih, const void* bhh, float* out, const int* flag) {
    int i = blockIdx.x * 256 + threadIdx.x;
    if (i < G4) out[i] = ldin(bih, i, *flag) + ldin(bhh, i, *flag);
}
__global__ void wsum_k(const void* a, const void* b, u16* o, const int* flag) {
    int i = blockIdx.x * 256 + threadIdx.x;
    if (i < H2 * H2) o[i] = f2us(ldin(a, i, *flag) + ldin(b, i, *flag));
}

// ---------------------------------------------------------------------------
// GEMM: C[M,N] = A[M,K] @ W[N,K]^T (+bias); A,W bf16; C f32 or bf16.
// ---------------------------------------------------------------------------
#define BM 128
#define BN 128
#define BK 32
#define LDT 40

__global__ __launch_bounds__(256)
void gemm_bt(const u16* __restrict__ A, int lda,
             const u16* __restrict__ W, int ldw,
             void* __restrict__ C, int ldc,
             const float* __restrict__ bias,
             int M, int N, int K, int outBf16)
{
    __shared__ alignas(16) short As[BM * LDT];
    __shared__ alignas(16) short Bs[BN * LDT];
    const int tid  = threadIdx.x;
    const int m0   = blockIdx.y * BM;
    const int n0   = blockIdx.x * BN;
    const int lane = tid & 63;
    const int wave = tid >> 6;
    const int wm   = wave >> 1, wn = wave & 1;
    const int quad = lane >> 4, mrow = lane & 15;

    floatx4 acc[4][4];
#pragma unroll
    for (int i = 0; i < 4; ++i)
#pragma unroll
        for (int j = 0; j < 4; ++j) { floatx4 z4 = {0.f,0.f,0.f,0.f}; acc[i][j] = z4; }

    for (int k0 = 0; k0 < K; k0 += BK) {
#pragma unroll
        for (int cc = 0; cc < 2; ++cc) {
            int c   = tid + cc * 256;
            int row = c >> 2;
            int kc  = (c & 3) << 3;
            int gk  = k0 + kc;
            {
                int gr = m0 + row;
                short8 v;
                if (gr < M && gk + 8 <= K) {
                    v = *(const short8*)(A + (size_t)gr * lda + gk);
                } else {
#pragma unroll
                    for (int e = 0; e < 8; ++e)
                        v[e] = (gr < M && (gk + e) < K) ? (short)A[(size_t)gr * lda + gk + e] : (short)0;
                }
                *(short8*)&As[row * LDT + kc] = v;
            }
            {
                int gn = n0 + row;
                short8 v;
                if (gn < N && gk + 8 <= K) {
                    v = *(const short8*)(W + (size_t)gn * ldw + gk);
                } else {
#pragma unroll
                    for (int e = 0; e < 8; ++e)
                        v[e] = (gn < N && (gk + e) < K) ? (short)W[(size_t)gn * ldw + gk + e] : (short)0;
                }
                *(short8*)&Bs[row * LDT + kc] = v;
            }
        }
        __syncthreads();

        short8 af[4], bf[4];
#pragma unroll
        for (int i = 0; i < 4; ++i)
            af[i] = *(const short8*)&As[(wm * 64 + i * 16 + mrow) * LDT + quad * 8];
#pragma unroll
        for (int j = 0; j < 4; ++j)
            bf[j] = *(const short8*)&Bs[(wn * 64 + j * 16 + mrow) * LDT + quad * 8];
#pragma unroll
        for (int i = 0; i < 4; ++i)
#pragma unroll
            for (int j = 0; j < 4; ++j)
                acc[i][j] = __builtin_amdgcn_mfma_f32_16x16x32_bf16(af[i], bf[j], acc[i][j], 0, 0, 0);
        __syncthreads();
    }

#pragma unroll
    for (int i = 0; i < 4; ++i)
#pragma unroll
        for (int j = 0; j < 4; ++j)
#pragma unroll
            for (int r = 0; r < 4; ++r) {
                int row = m0 + wm * 64 + i * 16 + quad * 4 + r;
                int col = n0 + wn * 64 + j * 16 + mrow;
                if (row < M && col < N) {
                    float v = acc[i][j][r];
                    if (bias) v += bias[col];
                    if (outBf16) ((u16*)C)[(size_t)row * ldc + col] = f2us(v);
                    else         ((float*)C)[(size_t)row * ldc + col] = v;
                }
            }
}

// ---------------------------------------------------------------------------
// LSTM recurrence: one 1024-thread WG per (seq n, dir). Gate order i,f,g,o.
// writeAtSource=1 -> write at source index tt (layer-2); 0 -> scan index t.
// ---------------------------------------------------------------------------
__global__ __launch_bounds__(1024)
void lstm_rec(const u16* __restrict__ xWf, const u16* __restrict__ xWb,
              const float* __restrict__ WhTf, const float* __restrict__ WhTb,
              int L,
              u16* __restrict__ hOut, int hStride,
              u16* __restrict__ cOut, int cStride,
              const int* __restrict__ lenp,
              int writeAtSource, int lastOnly)
{
    __shared__ float h_s[RR];
    __shared__ float c_s[RR];
    __shared__ float g_s[G4];
    const int n   = blockIdx.x;
    const int dir = blockIdx.y;
    const int g   = threadIdx.x;
    const u16* xW = dir ? xWb : xWf;
    const float* WT = dir ? WhTb : WhTf;
    const int colOff = dir * RR;

    if (g < RR) { h_s[g] = 0.f; c_s[g] = 0.f; }
    __syncthreads();

    for (int t = 0; t < L; ++t) {
        const int tt = dir ? (L - 1 - t) : t;
        float acc = us2f(xW[((size_t)n * L + tt) * G4 + g]);
        const float* w = WT + g;
#pragma unroll 8
        for (int k = 0; k < RR; ++k)
            acc += w[k << 10] * h_s[k];
        g_s[g] = acc;
        __syncthreads();
        if (g < RR) {
            float iv = g_s[g], fv = g_s[RR + g], gv = g_s[2 * RR + g], ov = g_s[3 * RR + g];
            float cn = sigm(fv) * c_s[g] + sigm(iv) * tanhf(gv);
            float hn = sigm(ov) * tanhf(cn);
            c_s[g] = cn; h_s[g] = hn;
            if (!lastOnly) {
                int wr = writeAtSource ? tt : t;
                float mk = (lenp && wr >= lenp[n]) ? 0.f : 1.f;
                size_t ro = (size_t)n * L + wr;
                hOut[ro * hStride + colOff + g] = f2us(hn * mk);
                if (cOut) cOut[ro * cStride + colOff + g] = f2us(cn * mk);
            }
        }
        __syncthreads();
    }
    if (lastOnly && g < RR)
        hOut[(size_t)n * hStride + colOff + g] = f2us(h_s[g]);
}

// ------------------------- small fused kernels -----------------------------
__global__ void hprev_k(const u16* __restrict__ G, u16* __restrict__ Hp) {
    int idx = blockIdx.x * 256 + threadIdx.x;
    if (idx < BT * H2) {
        int r = idx >> 9, d = idx & 511;
        int t = r & (TT - 1);
        Hp[idx] = (t == 0) ? (u16)0 : G[(size_t)(r - 1) * G4 + d];
    }
}
__global__ void s_k(const float* __restrict__ e, const u16* __restrict__ mB,
                    u16* __restrict__ sB) {
    int i = blockIdx.x * 256 + threadIdx.x;
    if (i < BT * H2) sB[i] = f2us(sigm(e[i]) * tanhf(us2f(mB[i])));
}
__global__ void z_k(const float* __restrict__ cWh, const float* __restrict__ cWu,
                    const float* __restrict__ Wv, float* __restrict__ z) {
    int idx = blockIdx.x * 256 + threadIdx.x;
    if (idx >= BT * SS) return;
    int r = idx >> 5, s = idx & 31;
    int b = r >> 9;
    const float* ph = cWh + (size_t)r * MDU_;
    const float* pu = cWu + (size_t)(b * SS + s) * MDU_;
    float acc = 0.f;
    for (int j = 0; j < MDU_; ++j) acc += tanhf(ph[j] + pu[j]) * Wv[j];
    z[idx] = acc;
}
__global__ void zhat_k(const float* __restrict__ sW, const float* __restrict__ cWh,
                       const float* __restrict__ Wv, float* __restrict__ zhat) {
    int r = blockIdx.x * 256 + threadIdx.x;
    if (r >= BT) return;
    float acc = 0.f;
    const float* ps = sW + (size_t)r * MDU_;
    const float* ph = cWh + (size_t)r * MDU_;
    for (int j = 0; j < MDU_; ++j) acc += tanhf(ps[j] + ph[j]) * Wv[j];
    zhat[r] = acc;
}
__global__ __launch_bounds__(64)
void attn_mix_k(const float* __restrict__ z, const float* __restrict__ zhat,
                const u16* __restrict__ U, const u16* __restrict__ sB,
                u16* __restrict__ G) {
    int r = blockIdx.x;
    int lane = threadIdx.x;
    int b = r >> 9;
    __shared__ float alpha[SS];
    float zv = (lane < SS) ? z[(size_t)r * SS + lane] : -1e30f;
    float mx = zv;
    for (int o = 32; o > 0; o >>= 1) mx = fmaxf(mx, __shfl_xor(mx, o));
    float ez = (lane < SS) ? expf(zv - mx) : 0.f;
    float s1 = ez;
    for (int o = 32; o > 0; o >>= 1) s1 += __shfl_xor(s1, o);
    float zh = zhat[r];
    float mx2 = fmaxf(mx, zh);
    float denom = s1 * expf(mx - mx2) + expf(zh - mx2);
    float beta = expf(zh - mx2) / denom;
    if (lane < SS) alpha[lane] = ez / s1;
    __syncthreads();
    for (int d = lane; d < H2; d += 64) {
        float cv = 0.f;
#pragma unroll 8
        for (int s2 = 0; s2 < SS; ++s2)
            cv += alpha[s2] * us2f(U[(size_t)(b * SS + s2) * H2 + d]);
        float sv = us2f(sB[(size_t)r * H2 + d]);
        G[(size_t)r * G4 + H2 + d] = f2us(beta * sv + (1.f - beta) * cv);
    }
}
__global__ __launch_bounds__(256)
void logit_k(const u16* __restrict__ G, const u16* __restrict__ Mb,
             const u16* __restrict__ Wout, const float* __restrict__ boutF,
             void* __restrict__ out, const int* __restrict__ flag) {
    int r = blockIdx.x * 4 + (threadIdx.x >> 6);
    if (r >= BT) return;
    int lane = threadIdx.x & 63;
    float acc[TAGS_] = {0, 0, 0, 0, 0, 0, 0};
    for (int k = lane; k < 1536; k += 64) {
        float v = (k < G4) ? us2f(G[(size_t)r * G4 + k]) : us2f(Mb[(size_t)r * H2 + (k - G4)]);
#pragma unroll
        for (int tg = 0; tg < TAGS_; ++tg) acc[tg] += v * us2f(Wout[tg * 1536 + k]);
    }
#pragma unroll
    for (int tg = 0; tg < TAGS_; ++tg) {
        float s = acc[tg];
        for (int o = 32; o > 0; o >>= 1) s += __shfl_xor(s, o);
        acc[tg] = s;
    }
    if (lane == 0) {
        int bf = *flag;
#pragma unroll
        for (int tg = 0; tg < TAGS_; ++tg) {
            float v = acc[tg] + boutF[tg];
            if (bf) ((u16*)out)[(size_t)r * TAGS_ + tg] = f2us(v);
            else    ((float*)out)[(size_t)r * TAGS_ + tg] = v;
        }
    }
}

// ---------------------------------------------------------------------------
extern "C" void kernel_launch(void* const* d_in, const int* in_sizes, int n_in,
                              void* d_out, int out_size, void* d_ws, size_t ws_size,
                              hipStream_t stream)
{
    const void* x_text = d_in[0];
    const void* x_syn  = d_in[1];
    const int* len_ctx = (const int*)d_in[3];
    const void *Wih[6], *Whh[6], *bih[6], *bhh[6];
    for (int l = 0; l < 6; ++l) {
        Wih[l] = d_in[5 + l * 4 + 0];
        Whh[l] = d_in[5 + l * 4 + 1];
        bih[l] = d_in[5 + l * 4 + 2];
        bhh[l] = d_in[5 + l * 4 + 3];
    }
    const void* W_cWh = d_in[29];
    const void* W_cWu = d_in[30];
    const void* W_v   = d_in[31];
    const void* W_sWh = d_in[32];
    const void* W_sWu = d_in[33];
    const void* W_Ws  = d_in[34];
    const void* W_out = d_in[35];
    const void* b_out = d_in[36];
    (void)in_sizes; (void)n_in; (void)out_size; (void)ws_size;

    // ---- workspace: persistent (~17.5MB) + BIG overlay region (24MB) ----
    char* ws = (char*)d_ws;
    size_t off = 0;
    auto alloc = [&](size_t bytes) -> void* {
        void* p = ws + off;
        off += (bytes + 255) & ~(size_t)255;
        return p;
    };
    int*   flagB  = (int*)alloc(256);
    float* bsum[6];
    for (int l = 0; l < 6; ++l) bsum[l] = (float*)alloc((size_t)G4 * 4);
    u16*   WsumB  = (u16*)alloc((size_t)H2 * H2 * 2);
    u16*   Ub     = (u16*)alloc((size_t)NSEQ * H2 * 2);
    u16*   Gb     = (u16*)alloc((size_t)BT * G4 * 2);
    u16*   mMb    = (u16*)alloc((size_t)BT * H2 * 2);   // m (L1 cells), later M (L2 h)
    float* cWhB   = (float*)alloc((size_t)BT * MDU_ * 4);
    float* cWuB   = (float*)alloc((size_t)NSEQ * MDU_ * 4);
    float* sWB    = (float*)alloc((size_t)BT * MDU_ * 4);
    float* zB     = (float*)alloc((size_t)BT * SS * 4);
    float* zhatB  = (float*)alloc((size_t)BT * 4);
    u16*   Wcwh16 = (u16*)alloc((size_t)MDU_ * H2 * 2);
    u16*   Wcwu16 = (u16*)alloc((size_t)MDU_ * H2 * 2);
    u16*   Wws16  = (u16*)alloc((size_t)MDU_ * H2 * 2);
    u16*   Wout16 = (u16*)alloc((size_t)TAGS_ * 1536 * 2);
    float* WvF    = (float*)alloc((size_t)MDU_ * 4);
    float* boutF  = (float*)alloc((size_t)TAGS_ * 4);
    char*  BIG    = (char*)alloc((size_t)24 * MB1);

    // phase A/B overlays
    u16*   bufA  = (u16*)BIG;                       // 8MB xW fwd
    u16*   bufB  = (u16*)(BIG + (size_t)8 * MB1);   // 8MB xW bwd
    u16*   x16   = (u16*)(BIG + (size_t)16 * MB1);  // 3.5MB input cast
    u16*   W16a  = (u16*)(BIG + (size_t)19 * MB1 + MB1 / 2);
    u16*   W16b  = (u16*)(BIG + (size_t)20 * MB1 + MB1 / 2);
    float* WhTa  = (float*)(BIG + (size_t)21 * MB1 + MB1 / 2);
    float* WhTb  = (float*)(BIG + (size_t)22 * MB1 + MB1 / 2);
    // phase C overlays
    u16*   HprevB = (u16*)BIG;                      // 4MB
    float* eBuf   = (float*)(BIG + (size_t)4 * MB1);   // 8MB
    u16*   sBuf   = (u16*)(BIG + (size_t)12 * MB1);    // 4MB
    // phase D overlays
    u16*   mxWf  = (u16*)BIG;
    u16*   mxWb  = (u16*)(BIG + (size_t)8 * MB1);
    u16*   W16aD = (u16*)(BIG + (size_t)16 * MB1);  // 2MB
    u16*   W16bD = (u16*)(BIG + (size_t)18 * MB1);  // 2MB
    float* WhTaD = (float*)(BIG + (size_t)20 * MB1);
    float* WhTbD = (float*)(BIG + (size_t)21 * MB1);

    auto cgrid = [](long n) { return dim3((unsigned)((n + 255) / 256)); };

    // ---- dtype probe + persistent casts ----
    detect_k<<<dim3(1), dim3(256), 0, stream>>>(x_text, flagB);
    castbf_k<<<cgrid(MDU_ * H2), dim3(256), 0, stream>>>(W_cWh, 0, Wcwh16, MDU_ * H2, flagB);
    castbf_k<<<cgrid(MDU_ * H2), dim3(256), 0, stream>>>(W_cWu, 0, Wcwu16, MDU_ * H2, flagB);
    castbf_k<<<cgrid(MDU_ * H2), dim3(256), 0, stream>>>(W_Ws, 0, Wws16, MDU_ * H2, flagB);
    castbf_k<<<cgrid(TAGS_ * 1536), dim3(256), 0, stream>>>(W_out, 0, Wout16, TAGS_ * 1536, flagB);
    castf_k<<<cgrid(MDU_), dim3(256), 0, stream>>>(W_v, WvF, MDU_, flagB);
    castf_k<<<cgrid(TAGS_), dim3(256), 0, stream>>>(b_out, boutF, TAGS_, flagB);
    for (int l = 0; l < 6; ++l)
        bias_sum_k<<<dim3(4), dim3(256), 0, stream>>>(bih[l], bhh[l], bsum[l], flagB);
    wsum_k<<<cgrid(H2 * H2), dim3(256), 0, stream>>>(W_sWh, W_sWu, WsumB, flagB);

    // ---- phase A: synopsis LSTMs -> U ----
    castbf_k<<<cgrid(G4 * DD), dim3(256), 0, stream>>>(Wih[2], 0, W16a, G4 * DD, flagB);
    castbf_k<<<cgrid(G4 * DD), dim3(256), 0, stream>>>(Wih[3], 0, W16b, G4 * DD, flagB);
    whh_t_k<<<cgrid(G4 * RR), dim3(256), 0, stream>>>(Whh[2], WhTa, flagB);
    whh_t_k<<<cgrid(G4 * RR), dim3(256), 0, stream>>>(Whh[3], WhTb, flagB);
    for (int c = 0; c < NSEQ / SCH; ++c) {
        long chunkElems = (long)SCH * JJ * DD;
        castbf_k<<<cgrid(chunkElems), dim3(256), 0, stream>>>(x_syn, (long)c * chunkElems, x16, chunkElems, flagB);
        gemm_bt<<<dim3(8, (SCH * JJ) / BM), dim3(256), 0, stream>>>(x16, DD, W16a, DD, bufA, G4, bsum[2], SCH * JJ, G4, DD, 1);
        gemm_bt<<<dim3(8, (SCH * JJ) / BM), dim3(256), 0, stream>>>(x16, DD, W16b, DD, bufB, G4, bsum[3], SCH * JJ, G4, DD, 1);
        lstm_rec<<<dim3(SCH, 2), dim3(1024), 0, stream>>>(bufA, bufB, WhTa, WhTb, JJ,
            Ub + (size_t)c * SCH * H2, H2, (u16*)nullptr, 0, (const int*)nullptr, 0, 1);
    }

    // ---- phase B: context layer-1 -> H (Gb left), m (mMb) ----
    castbf_k<<<cgrid((long)BT * DD), dim3(256), 0, stream>>>(x_text, 0, x16, (long)BT * DD, flagB);
    castbf_k<<<cgrid(G4 * DD), dim3(256), 0, stream>>>(Wih[0], 0, W16a, G4 * DD, flagB);
    castbf_k<<<cgrid(G4 * DD), dim3(256), 0, stream>>>(Wih[1], 0, W16b, G4 * DD, flagB);
    whh_t_k<<<cgrid(G4 * RR), dim3(256), 0, stream>>>(Whh[0], WhTa, flagB);
    whh_t_k<<<cgrid(G4 * RR), dim3(256), 0, stream>>>(Whh[1], WhTb, flagB);
    gemm_bt<<<dim3(8, 32), dim3(256), 0, stream>>>(x16, DD, W16a, DD, bufA, G4, bsum[0], BT, G4, DD, 1);
    gemm_bt<<<dim3(8, 32), dim3(256), 0, stream>>>(x16, DD, W16b, DD, bufB, G4, bsum[1], BT, G4, DD, 1);
    lstm_rec<<<dim3(BB, 2), dim3(1024), 0, stream>>>(bufA, bufB, WhTa, WhTb, TT,
        Gb, G4, mMb, H2, len_ctx, 0, 0);

    // ---- phase C: attention ----
    gemm_bt<<<dim3(1, 32), dim3(256), 0, stream>>>(Gb, G4, Wcwh16, H2, cWhB, MDU_, nullptr, BT, MDU_, H2, 0);
    gemm_bt<<<dim3(1, 2),  dim3(256), 0, stream>>>(Ub, H2, Wcwu16, H2, cWuB, MDU_, nullptr, NSEQ, MDU_, H2, 0);
    hprev_k<<<cgrid(BT * H2), dim3(256), 0, stream>>>(Gb, HprevB);
    gemm_bt<<<dim3(4, 32), dim3(256), 0, stream>>>(HprevB, H2, WsumB, H2, eBuf, H2, nullptr, BT, H2, H2, 0);
    s_k<<<cgrid(BT * H2), dim3(256), 0, stream>>>(eBuf, mMb, sBuf);
    gemm_bt<<<dim3(1, 32), dim3(256), 0, stream>>>(sBuf, H2, Wws16, H2, sWB, MDU_, nullptr, BT, MDU_, H2, 0);
    z_k<<<cgrid(BT * SS), dim3(256), 0, stream>>>(cWhB, cWuB, WvF, zB);
    zhat_k<<<cgrid(BT), dim3(256), 0, stream>>>(sWB, cWhB, WvF, zhatB);
    attn_mix_k<<<dim3(BT), dim3(64), 0, stream>>>(zB, zhatB, Ub, sBuf, Gb);

    // ---- phase D: layer-2 LSTMs over G -> M (into mMb) ----
    castbf_k<<<cgrid(G4 * G4), dim3(256), 0, stream>>>(Wih[4], 0, W16aD, G4 * G4, flagB);
    castbf_k<<<cgrid(G4 * G4), dim3(256), 0, stream>>>(Wih[5], 0, W16bD, G4 * G4, flagB);
    whh_t_k<<<cgrid(G4 * RR), dim3(256), 0, stream>>>(Whh[4], WhTaD, flagB);
    whh_t_k<<<cgrid(G4 * RR), dim3(256), 0, stream>>>(Whh[5], WhTbD, flagB);
    gemm_bt<<<dim3(8, 32), dim3(256), 0, stream>>>(Gb, G4, W16aD, G4, mxWf, G4, bsum[4], BT, G4, G4, 1);
    gemm_bt<<<dim3(8, 32), dim3(256), 0, stream>>>(Gb, G4, W16bD, G4, mxWb, G4, bsum[5], BT, G4, G4, 1);
    lstm_rec<<<dim3(BB, 2), dim3(1024), 0, stream>>>(mxWf, mxWb, WhTaD, WhTbD, TT,
        mMb, H2, (u16*)nullptr, 0, (const int*)nullptr, 1, 0);

    // ---- output ----
    logit_k<<<dim3(BT / 4), dim3(256), 0, stream>>>(Gb, mMb, Wout16, boutF, d_out, flagB);
}

// Round 4
// 7300.263 us; speedup vs baseline: 1.6702x; 1.6702x over previous
//
#include <hip/hip_runtime.h>
#include <math.h>
#include <stddef.h>

// ---------------------------------------------------------------------------
// ATT_SYN: bi-LSTM encoder + synopsis attention + 2nd bi-LSTM + tag head.
// B=8 T=512 S=32 J=64 D=400 R=256 MDU=100 TAGS=7
// Inputs fp32 (detected at runtime; dtype-agnostic). Internals: bf16 MFMA
// GEMMs (fp32 accum). Recurrence: cooperative 4-WG-per-direction kernel with
// weight B-fragments RESIDENT IN VGPRS (128/lane) and a device-scope spin
// barrier per step (weights never re-read -> kills the 10ms L2 streaming).
// ---------------------------------------------------------------------------

#define BB 8
#define TT 512
#define SS 32
#define JJ 64
#define DD 400
#define RR 256
#define G4 1024
#define H2 512
#define MDU_ 100
#define TAGS_ 7
#define BT (BB*TT)
#define NSEQ (BB*SS)
#define SCH 64
#define MB1 (1024*1024)

typedef __attribute__((ext_vector_type(8))) short short8;
typedef __attribute__((ext_vector_type(4))) float floatx4;
typedef __attribute__((ext_vector_type(4))) unsigned int u32x4;
typedef unsigned short u16;
typedef unsigned int u32;

__device__ __forceinline__ float us2f(u16 u) {
    unsigned int v = ((unsigned int)u) << 16;
    return __builtin_bit_cast(float, v);
}
__device__ __forceinline__ u16 f2us(float f) {
    unsigned int v = __builtin_bit_cast(unsigned int, f);
    v += 0x7FFFu + ((v >> 16) & 1u);
    return (u16)(v >> 16);
}
__device__ __forceinline__ float ldin(const void* p, long i, int bf) {
    return bf ? us2f(((const u16*)p)[i]) : ((const float*)p)[i];
}
__device__ __forceinline__ float sigm(float x) { return 1.0f / (1.0f + expf(-x)); }

// ---- dtype probe ----
__global__ void detect_k(const void* x, int* flag) {
    __shared__ int cnt;
    if (threadIdx.x == 0) cnt = 0;
    __syncthreads();
    u16 lo = ((const u16*)x)[threadIdx.x * 2];
    int e = (lo >> 7) & 0xFF;
    if (e >= 118 && e <= 131) atomicAdd(&cnt, 1);
    __syncthreads();
    if (threadIdx.x == 0) *flag = (cnt > 128) ? 1 : 0;
}
__global__ void castbf_k(const void* src, long off, u16* dst, long n, const int* flag) {
    long i = (long)blockIdx.x * 256 + threadIdx.x;
    if (i < n) dst[i] = (*flag) ? ((const u16*)src)[off + i] : f2us(((const float*)src)[off + i]);
}
__global__ void castf_k(const void* src, float* dst, long n, const int* flag) {
    long i = (long)blockIdx.x * 256 + threadIdx.x;
    if (i < n) dst[i] = ldin(src, i, *flag);
}
__global__ void zero_k(u32* p, long n) {
    long i = (long)blockIdx.x * 256 + threadIdx.x;
    if (i < n) p[i] = 0u;
}
__global__ void bias_sum_k(const void* bih, const void* bhh, float* out, const int* flag) {
    int i = blockIdx.x * 256 + threadIdx.x;
    if (i < G4) out[i] = ldin(bih, i, *flag) + ldin(bhh, i, *flag);
}
__global__ void wsum_k(const void* a, const void* b, u16* o, const int* flag) {
    int i = blockIdx.x * 256 + threadIdx.x;
    if (i < H2 * H2) o[i] = f2us(ldin(a, i, *flag) + ldin(b, i, *flag));
}
// Whh [1024,256] -> pre-swizzled MFMA B-fragments:
// WF[((((s*4+w)*4+t)*8+c)*64+lane)*8+j] = Whh[(w*256+s*64+t*16+(lane&15))*256
//                                              + c*32+(lane>>4)*8+j]
__global__ void whh_frag_k(const void* Whh, u16* WF, const int* flag) {
    int i = blockIdx.x * 256 + threadIdx.x;
    if (i >= 4 * 4 * 4 * 8 * 64 * 8) return;
    int j  = i & 7;
    int ln = (i >> 3) & 63;
    int c  = (i >> 9) & 7;
    int t  = (i >> 12) & 3;
    int w  = (i >> 14) & 3;
    int s  = (i >> 16) & 3;
    int n_g = w * 256 + s * 64 + t * 16 + (ln & 15);
    int k   = c * 32 + (ln >> 4) * 8 + j;
    WF[i] = f2us(ldin(Whh, (long)n_g * 256 + k, *flag));
}

// ---------------------------------------------------------------------------
// GEMM: C[M,N] = A[M,K] @ W[N,K]^T (+bias); A,W bf16; C f32 or bf16.
// ---------------------------------------------------------------------------
#define BM 128
#define BN 128
#define BK 32
#define LDT 40

__global__ __launch_bounds__(256)
void gemm_bt(const u16* __restrict__ A, int lda,
             const u16* __restrict__ W, int ldw,
             void* __restrict__ C, int ldc,
             const float* __restrict__ bias,
             int M, int N, int K, int outBf16)
{
    __shared__ alignas(16) short As[BM * LDT];
    __shared__ alignas(16) short Bs[BN * LDT];
    const int tid  = threadIdx.x;
    const int m0   = blockIdx.y * BM;
    const int n0   = blockIdx.x * BN;
    const int lane = tid & 63;
    const int wave = tid >> 6;
    const int wm   = wave >> 1, wn = wave & 1;
    const int quad = lane >> 4, mrow = lane & 15;

    floatx4 acc[4][4];
#pragma unroll
    for (int i = 0; i < 4; ++i)
#pragma unroll
        for (int j = 0; j < 4; ++j) { floatx4 z4 = {0.f,0.f,0.f,0.f}; acc[i][j] = z4; }

    for (int k0 = 0; k0 < K; k0 += BK) {
#pragma unroll
        for (int cc = 0; cc < 2; ++cc) {
            int c   = tid + cc * 256;
            int row = c >> 2;
            int kc  = (c & 3) << 3;
            int gk  = k0 + kc;
            {
                int gr = m0 + row;
                short8 v;
                if (gr < M && gk + 8 <= K) {
                    v = *(const short8*)(A + (size_t)gr * lda + gk);
                } else {
#pragma unroll
                    for (int e = 0; e < 8; ++e)
                        v[e] = (gr < M && (gk + e) < K) ? (short)A[(size_t)gr * lda + gk + e] : (short)0;
                }
                *(short8*)&As[row * LDT + kc] = v;
            }
            {
                int gn = n0 + row;
                short8 v;
                if (gn < N && gk + 8 <= K) {
                    v = *(const short8*)(W + (size_t)gn * ldw + gk);
                } else {
#pragma unroll
                    for (int e = 0; e < 8; ++e)
                        v[e] = (gn < N && (gk + e) < K) ? (short)W[(size_t)gn * ldw + gk + e] : (short)0;
                }
                *(short8*)&Bs[row * LDT + kc] = v;
            }
        }
        __syncthreads();

        short8 af[4], bf[4];
#pragma unroll
        for (int i = 0; i < 4; ++i)
            af[i] = *(const short8*)&As[(wm * 64 + i * 16 + mrow) * LDT + quad * 8];
#pragma unroll
        for (int j = 0; j < 4; ++j)
            bf[j] = *(const short8*)&Bs[(wn * 64 + j * 16 + mrow) * LDT + quad * 8];
#pragma unroll
        for (int i = 0; i < 4; ++i)
#pragma unroll
            for (int j = 0; j < 4; ++j)
                acc[i][j] = __builtin_amdgcn_mfma_f32_16x16x32_bf16(af[i], bf[j], acc[i][j], 0, 0, 0);
        __syncthreads();
    }

#pragma unroll
    for (int i = 0; i < 4; ++i)
#pragma unroll
        for (int j = 0; j < 4; ++j)
#pragma unroll
            for (int r = 0; r < 4; ++r) {
                int row = m0 + wm * 64 + i * 16 + quad * 4 + r;
                int col = n0 + wn * 64 + j * 16 + mrow;
                if (row < M && col < N) {
                    float v = acc[i][j][r];
                    if (bias) v += bias[col];
                    if (outBf16) ((u16*)C)[(size_t)row * ldc + col] = f2us(v);
                    else         ((float*)C)[(size_t)row * ldc + col] = v;
                }
            }
}

// ---------------------------------------------------------------------------
// Cooperative LSTM: grid (4 slices, 2 dirs, nbatch). Group = (dir,batch) of 4
// slice-WGs; each WG: 256 thr (4 waves), wave w = gate type, holds its 64x256
// bf16 Whh slice in 128 VGPRs as B-fragments. M=8 seqs/WG. h exchanged via
// double-buffered global hx (relaxed agent atomics) + spin barrier per step.
// ---------------------------------------------------------------------------
__global__ __launch_bounds__(256, 1)
void lstm_coop(const u16* __restrict__ xWf, const u16* __restrict__ xWb,
               const u16* __restrict__ WFf, const u16* __restrict__ WFb,
               int L,
               u16* __restrict__ hOut, int hStride,
               u16* __restrict__ cOut, int cStride,
               const int* __restrict__ lenp,
               int writeAtSource, int lastOnly, int seqBase,
               u32* __restrict__ hx32, u32* __restrict__ cnts, int cntBase)
{
    const int s   = blockIdx.x;        // slice
    const int dir = blockIdx.y;
    const int bat = blockIdx.z;
    const int nb  = gridDim.z;
    const int tid = threadIdx.x;
    const int wv  = tid >> 6;          // gate type i,f,g,o
    const int ln  = tid & 63;
    const int q   = ln >> 4, m = ln & 15;
    const u16* xW = dir ? xWb : xWf;
    const u16* WF = dir ? WFb : WFf;
    const int grp = cntBase + dir * nb + bat;
    u32* cnt = cnts + (size_t)grp * 16;
    u32* hx  = hx32 + (size_t)grp * 2048;   // [2][8 seq][128 u32]

    __shared__ float g_s[4 * 8 * 64];
    __shared__ float c_s[8 * 64];

    // resident B fragments: 4 N-tiles x 8 K-chunks, 16B/lane each = 128 VGPRs
    short8 bw[4][8];
    {
        const u16* wb = WF + ((size_t)(s * 4 + wv) * 32) * 512 + ln * 8;
#pragma unroll
        for (int t4 = 0; t4 < 4; ++t4)
#pragma unroll
            for (int c = 0; c < 8; ++c)
                bw[t4][c] = *(const short8*)(wb + (size_t)(t4 * 8 + c) * 512);
    }
    for (int i = tid; i < 512; i += 256) c_s[i] = 0.f;
    __syncthreads();

    const int seqU = tid >> 5;             // update phase: seq 0..7
    const int j0   = (tid & 31) * 2;       // j pair

    for (int t = 0; t < L; ++t) {
        const int tt = dir ? (L - 1 - t) : t;
        // A fragments from hx[(t-1)&1]
        short8 a[8];
        if (t > 0) {
            const u32* hp = hx + ((t - 1) & 1) * 1024 + m * 128;
#pragma unroll
            for (int c = 0; c < 8; ++c) {
                if (m < 8) {
                    u32x4 v = *(const u32x4*)(hp + c * 16 + q * 4);
                    a[c] = __builtin_bit_cast(short8, v);
                } else {
                    short8 z = {0,0,0,0,0,0,0,0}; a[c] = z;
                }
            }
        } else {
            short8 z = {0,0,0,0,0,0,0,0};
#pragma unroll
            for (int c = 0; c < 8; ++c) a[c] = z;
        }
        floatx4 acc[4];
#pragma unroll
        for (int t4 = 0; t4 < 4; ++t4) { floatx4 z4 = {0.f,0.f,0.f,0.f}; acc[t4] = z4; }
#pragma unroll
        for (int t4 = 0; t4 < 4; ++t4)
#pragma unroll
            for (int c = 0; c < 8; ++c)
                acc[t4] = __builtin_amdgcn_mfma_f32_16x16x32_bf16(a[c], bw[t4][c], acc[t4], 0, 0, 0);
        // C layout: seq = q*4+r (valid q<2), col n = t4*16 + m
        if (q < 2) {
#pragma unroll
            for (int t4 = 0; t4 < 4; ++t4)
#pragma unroll
                for (int r = 0; r < 4; ++r)
                    g_s[(wv * 8 + q * 4 + r) * 64 + t4 * 16 + m] = acc[t4][r];
        }
        __syncthreads();
        // gate fuse + state update: thread -> (seqU, j0..j0+1)
        {
            size_t rl = ((size_t)(bat * 8 + seqU)) * L + tt;
            const u16* xr = xW + rl * G4;
            float hn2[2], cn2[2];
#pragma unroll
            for (int e = 0; e < 2; ++e) {
                int j = j0 + e;
                int col = s * 64 + j;
                float iv = g_s[(0 * 8 + seqU) * 64 + j] + us2f(xr[col]);
                float fv = g_s[(1 * 8 + seqU) * 64 + j] + us2f(xr[256 + col]);
                float gv = g_s[(2 * 8 + seqU) * 64 + j] + us2f(xr[512 + col]);
                float ov = g_s[(3 * 8 + seqU) * 64 + j] + us2f(xr[768 + col]);
                float cold = c_s[seqU * 64 + j];
                float cn = sigm(fv) * cold + sigm(iv) * tanhf(gv);
                float hn = sigm(ov) * tanhf(cn);
                c_s[seqU * 64 + j] = cn;
                hn2[e] = hn; cn2[e] = cn;
            }
            u32 hpack = (u32)f2us(hn2[0]) | ((u32)f2us(hn2[1]) << 16);
            __hip_atomic_store(hx + (t & 1) * 1024 + seqU * 128 + ((s * 64 + j0) >> 1),
                               hpack, __ATOMIC_RELAXED, __HIP_MEMORY_SCOPE_AGENT);
            if (!lastOnly) {
                int wr = writeAtSource ? tt : t;
                float mk = (lenp && wr >= lenp[bat * 8 + seqU]) ? 0.f : 1.f;
                size_t ro = ((size_t)(bat * 8 + seqU)) * L + wr;
                u32 hp2 = (u32)f2us(hn2[0] * mk) | ((u32)f2us(hn2[1] * mk) << 16);
                *(u32*)(hOut + ro * hStride + dir * RR + s * 64 + j0) = hp2;
                if (cOut) {
                    u32 cp2 = (u32)f2us(cn2[0] * mk) | ((u32)f2us(cn2[1] * mk) << 16);
                    *(u32*)(cOut + ro * cStride + dir * RR + s * 64 + j0) = cp2;
                }
            } else if (t == L - 1) {
                size_t ro = (size_t)(seqBase + bat * 8 + seqU);
                u32 hp2 = (u32)f2us(hn2[0]) | ((u32)f2us(hn2[1]) << 16);
                *(u32*)(hOut + ro * hStride + dir * RR + s * 64 + j0) = hp2;
            }
        }
        // inter-WG barrier (4 slice-WGs per group)
        __threadfence();
        __syncthreads();
        if (tid == 0) {
            __hip_atomic_fetch_add(cnt, 1u, __ATOMIC_RELEASE, __HIP_MEMORY_SCOPE_AGENT);
            u32 tgt = 4u * (u32)(t + 1);
            long guard = 0;
            while (__hip_atomic_load(cnt, __ATOMIC_ACQUIRE, __HIP_MEMORY_SCOPE_AGENT) < tgt) {
                __builtin_amdgcn_s_sleep(1);
                if (++guard > (1L << 19)) break;   // diagnostic bail, never in healthy runs
            }
        }
        __syncthreads();
    }
}

// ------------------------- small fused kernels -----------------------------
__global__ void hprev_k(const u16* __restrict__ G, u16* __restrict__ Hp) {
    int idx = blockIdx.x * 256 + threadIdx.x;
    if (idx < BT * H2) {
        int r = idx >> 9, d = idx & 511;
        int t = r & (TT - 1);
        Hp[idx] = (t == 0) ? (u16)0 : G[(size_t)(r - 1) * G4 + d];
    }
}
__global__ void s_k(const float* __restrict__ e, const u16* __restrict__ mB,
                    u16* __restrict__ sB) {
    int i = blockIdx.x * 256 + threadIdx.x;
    if (i < BT * H2) sB[i] = f2us(sigm(e[i]) * tanhf(us2f(mB[i])));
}
__global__ void z_k(const float* __restrict__ cWh, const float* __restrict__ cWu,
                    const float* __restrict__ Wv, float* __restrict__ z) {
    int idx = blockIdx.x * 256 + threadIdx.x;
    if (idx >= BT * SS) return;
    int r = idx >> 5, s = idx & 31;
    int b = r >> 9;
    const float* ph = cWh + (size_t)r * MDU_;
    const float* pu = cWu + (size_t)(b * SS + s) * MDU_;
    float acc = 0.f;
    for (int j = 0; j < MDU_; ++j) acc += tanhf(ph[j] + pu[j]) * Wv[j];
    z[idx] = acc;
}
__global__ void zhat_k(const float* __restrict__ sW, const float* __restrict__ cWh,
                       const float* __restrict__ Wv, float* __restrict__ zhat) {
    int r = blockIdx.x * 256 + threadIdx.x;
    if (r >= BT) return;
    float acc = 0.f;
    const float* ps = sW + (size_t)r * MDU_;
    const float* ph = cWh + (size_t)r * MDU_;
    for (int j = 0; j < MDU_; ++j) acc += tanhf(ps[j] + ph[j]) * Wv[j];
    zhat[r] = acc;
}
__global__ __launch_bounds__(64)
void attn_mix_k(const float* __restrict__ z, const float* __restrict__ zhat,
                const u16* __restrict__ U, const u16* __restrict__ sB,
                u16* __restrict__ G) {
    int r = blockIdx.x;
    int lane = threadIdx.x;
    int b = r >> 9;
    __shared__ float alpha[SS];
    float zv = (lane < SS) ? z[(size_t)r * SS + lane] : -1e30f;
    float mx = zv;
    for (int o = 32; o > 0; o >>= 1) mx = fmaxf(mx, __shfl_xor(mx, o));
    float ez = (lane < SS) ? expf(zv - mx) : 0.f;
    float s1 = ez;
    for (int o = 32; o > 0; o >>= 1) s1 += __shfl_xor(s1, o);
    float zh = zhat[r];
    float mx2 = fmaxf(mx, zh);
    float denom = s1 * expf(mx - mx2) + expf(zh - mx2);
    float beta = expf(zh - mx2) / denom;
    if (lane < SS) alpha[lane] = ez / s1;
    __syncthreads();
    for (int d = lane; d < H2; d += 64) {
        float cv = 0.f;
#pragma unroll 8
        for (int s2 = 0; s2 < SS; ++s2)
            cv += alpha[s2] * us2f(U[(size_t)(b * SS + s2) * H2 + d]);
        float sv = us2f(sB[(size_t)r * H2 + d]);
        G[(size_t)r * G4 + H2 + d] = f2us(beta * sv + (1.f - beta) * cv);
    }
}
__global__ __launch_bounds__(256)
void logit_k(const u16* __restrict__ G, const u16* __restrict__ Mb,
             const u16* __restrict__ Wout, const float* __restrict__ boutF,
             void* __restrict__ out, const int* __restrict__ flag) {
    int r = blockIdx.x * 4 + (threadIdx.x >> 6);
    if (r >= BT) return;
    int lane = threadIdx.x & 63;
    float acc[TAGS_] = {0, 0, 0, 0, 0, 0, 0};
    for (int k = lane; k < 1536; k += 64) {
        float v = (k < G4) ? us2f(G[(size_t)r * G4 + k]) : us2f(Mb[(size_t)r * H2 + (k - G4)]);
#pragma unroll
        for (int tg = 0; tg < TAGS_; ++tg) acc[tg] += v * us2f(Wout[tg * 1536 + k]);
    }
#pragma unroll
    for (int tg = 0; tg < TAGS_; ++tg) {
        float s = acc[tg];
        for (int o = 32; o > 0; o >>= 1) s += __shfl_xor(s, o);
        acc[tg] = s;
    }
    if (lane == 0) {
        int bf = *flag;
#pragma unroll
        for (int tg = 0; tg < TAGS_; ++tg) {
            float v = acc[tg] + boutF[tg];
            if (bf) ((u16*)out)[(size_t)r * TAGS_ + tg] = f2us(v);
            else    ((float*)out)[(size_t)r * TAGS_ + tg] = v;
        }
    }
}

// ---------------------------------------------------------------------------
extern "C" void kernel_launch(void* const* d_in, const int* in_sizes, int n_in,
                              void* d_out, int out_size, void* d_ws, size_t ws_size,
                              hipStream_t stream)
{
    const void* x_text = d_in[0];
    const void* x_syn  = d_in[1];
    const int* len_ctx = (const int*)d_in[3];
    const void *Wih[6], *Whh[6], *bih[6], *bhh[6];
    for (int l = 0; l < 6; ++l) {
        Wih[l] = d_in[5 + l * 4 + 0];
        Whh[l] = d_in[5 + l * 4 + 1];
        bih[l] = d_in[5 + l * 4 + 2];
        bhh[l] = d_in[5 + l * 4 + 3];
    }
    const void* W_cWh = d_in[29];
    const void* W_cWu = d_in[30];
    const void* W_v   = d_in[31];
    const void* W_sWh = d_in[32];
    const void* W_sWu = d_in[33];
    const void* W_Ws  = d_in[34];
    const void* W_out = d_in[35];
    const void* b_out = d_in[36];
    (void)in_sizes; (void)n_in; (void)out_size; (void)ws_size;

    char* ws = (char*)d_ws;
    size_t off = 0;
    auto alloc = [&](size_t bytes) -> void* {
        void* p = ws + off;
        off += (bytes + 255) & ~(size_t)255;
        return p;
    };
    int*   flagB  = (int*)alloc(256);
    float* bsum[6];
    for (int l = 0; l < 6; ++l) bsum[l] = (float*)alloc((size_t)G4 * 4);
    u16*   WsumB  = (u16*)alloc((size_t)H2 * H2 * 2);
    u16*   Ub     = (u16*)alloc((size_t)NSEQ * H2 * 2);
    u16*   Gb     = (u16*)alloc((size_t)BT * G4 * 2);
    u16*   mMb    = (u16*)alloc((size_t)BT * H2 * 2);
    float* cWhB   = (float*)alloc((size_t)BT * MDU_ * 4);
    float* cWuB   = (float*)alloc((size_t)NSEQ * MDU_ * 4);
    float* sWB    = (float*)alloc((size_t)BT * MDU_ * 4);
    float* zB     = (float*)alloc((size_t)BT * SS * 4);
    float* zhatB  = (float*)alloc((size_t)BT * 4);
    u16*   Wcwh16 = (u16*)alloc((size_t)MDU_ * H2 * 2);
    u16*   Wcwu16 = (u16*)alloc((size_t)MDU_ * H2 * 2);
    u16*   Wws16  = (u16*)alloc((size_t)MDU_ * H2 * 2);
    u16*   Wout16 = (u16*)alloc((size_t)TAGS_ * 1536 * 2);
    float* WvF    = (float*)alloc((size_t)MDU_ * 4);
    float* boutF  = (float*)alloc((size_t)TAGS_ * 4);
    u16*   WF[6];
    for (int l = 0; l < 6; ++l) WF[l] = (u16*)alloc((size_t)G4 * RR * 2);   // 512KB each
    u32*   cnts   = (u32*)alloc((size_t)128 * 16 * 4);                      // padded counters
    u32*   hx32   = (u32*)alloc((size_t)128 * 2048 * 4);                    // 1MB h exchange
    char*  BIG    = (char*)alloc((size_t)24 * MB1);

    // BIG overlays
    u16*   bufA  = (u16*)BIG;
    u16*   bufB  = (u16*)(BIG + (size_t)8 * MB1);
    u16*   x16   = (u16*)(BIG + (size_t)16 * MB1);
    u16*   W16a  = (u16*)(BIG + (size_t)19 * MB1 + MB1 / 2);
    u16*   W16b  = (u16*)(BIG + (size_t)20 * MB1 + MB1 / 2);
    u16*   HprevB = (u16*)BIG;
    float* eBuf   = (float*)(BIG + (size_t)4 * MB1);
    u16*   sBuf   = (u16*)(BIG + (size_t)12 * MB1);
    u16*   mxWf  = (u16*)BIG;
    u16*   mxWb  = (u16*)(BIG + (size_t)8 * MB1);
    u16*   W16aD = (u16*)(BIG + (size_t)16 * MB1);
    u16*   W16bD = (u16*)(BIG + (size_t)18 * MB1);

    auto cgrid = [](long n) { return dim3((unsigned)((n + 255) / 256)); };

    // ---- prep ----
    detect_k<<<dim3(1), dim3(256), 0, stream>>>(x_text, flagB);
    zero_k<<<cgrid(128 * 16), dim3(256), 0, stream>>>(cnts, 128 * 16);
    castbf_k<<<cgrid(MDU_ * H2), dim3(256), 0, stream>>>(W_cWh, 0, Wcwh16, MDU_ * H2, flagB);
    castbf_k<<<cgrid(MDU_ * H2), dim3(256), 0, stream>>>(W_cWu, 0, Wcwu16, MDU_ * H2, flagB);
    castbf_k<<<cgrid(MDU_ * H2), dim3(256), 0, stream>>>(W_Ws, 0, Wws16, MDU_ * H2, flagB);
    castbf_k<<<cgrid(TAGS_ * 1536), dim3(256), 0, stream>>>(W_out, 0, Wout16, TAGS_ * 1536, flagB);
    castf_k<<<cgrid(MDU_), dim3(256), 0, stream>>>(W_v, WvF, MDU_, flagB);
    castf_k<<<cgrid(TAGS_), dim3(256), 0, stream>>>(b_out, boutF, TAGS_, flagB);
    for (int l = 0; l < 6; ++l) {
        bias_sum_k<<<dim3(4), dim3(256), 0, stream>>>(bih[l], bhh[l], bsum[l], flagB);
        whh_frag_k<<<dim3(1024), dim3(256), 0, stream>>>(Whh[l], WF[l], flagB);
    }
    wsum_k<<<cgrid(H2 * H2), dim3(256), 0, stream>>>(W_sWh, W_sWu, WsumB, flagB);

    // ---- phase A: synopsis (4 chunks of 64 seqs) -> U ----
    castbf_k<<<cgrid(G4 * DD), dim3(256), 0, stream>>>(Wih[2], 0, W16a, G4 * DD, flagB);
    castbf_k<<<cgrid(G4 * DD), dim3(256), 0, stream>>>(Wih[3], 0, W16b, G4 * DD, flagB);
    for (int c = 0; c < NSEQ / SCH; ++c) {
        long chunkElems = (long)SCH * JJ * DD;
        castbf_k<<<cgrid(chunkElems), dim3(256), 0, stream>>>(x_syn, (long)c * chunkElems, x16, chunkElems, flagB);
        gemm_bt<<<dim3(8, (SCH * JJ) / BM), dim3(256), 0, stream>>>(x16, DD, W16a, DD, bufA, G4, bsum[2], SCH * JJ, G4, DD, 1);
        gemm_bt<<<dim3(8, (SCH * JJ) / BM), dim3(256), 0, stream>>>(x16, DD, W16b, DD, bufB, G4, bsum[3], SCH * JJ, G4, DD, 1);
        lstm_coop<<<dim3(4, 2, 8), dim3(256), 0, stream>>>(
            bufA, bufB, WF[2], WF[3], JJ,
            Ub, H2, (u16*)nullptr, 0, (const int*)nullptr,
            0, 1, c * SCH, hx32, cnts, 2 + c * 16);
    }

    // ---- phase B: context layer-1 -> H (Gb left), m (mMb) ----
    castbf_k<<<cgrid((long)BT * DD), dim3(256), 0, stream>>>(x_text, 0, x16, (long)BT * DD, flagB);
    castbf_k<<<cgrid(G4 * DD), dim3(256), 0, stream>>>(Wih[0], 0, W16a, G4 * DD, flagB);
    castbf_k<<<cgrid(G4 * DD), dim3(256), 0, stream>>>(Wih[1], 0, W16b, G4 * DD, flagB);
    gemm_bt<<<dim3(8, 32), dim3(256), 0, stream>>>(x16, DD, W16a, DD, bufA, G4, bsum[0], BT, G4, DD, 1);
    gemm_bt<<<dim3(8, 32), dim3(256), 0, stream>>>(x16, DD, W16b, DD, bufB, G4, bsum[1], BT, G4, DD, 1);
    lstm_coop<<<dim3(4, 2, 1), dim3(256), 0, stream>>>(
        bufA, bufB, WF[0], WF[1], TT,
        Gb, G4, mMb, H2, len_ctx, 0, 0, 0, hx32, cnts, 0);

    // ---- phase C: attention ----
    gemm_bt<<<dim3(1, 32), dim3(256), 0, stream>>>(Gb, G4, Wcwh16, H2, cWhB, MDU_, nullptr, BT, MDU_, H2, 0);
    gemm_bt<<<dim3(1, 2),  dim3(256), 0, stream>>>(Ub, H2, Wcwu16, H2, cWuB, MDU_, nullptr, NSEQ, MDU_, H2, 0);
    hprev_k<<<cgrid(BT * H2), dim3(256), 0, stream>>>(Gb, HprevB);
    gemm_bt<<<dim3(4, 32), dim3(256), 0, stream>>>(HprevB, H2, WsumB, H2, eBuf, H2, nullptr, BT, H2, H2, 0);
    s_k<<<cgrid(BT * H2), dim3(256), 0, stream>>>(eBuf, mMb, sBuf);
    gemm_bt<<<dim3(1, 32), dim3(256), 0, stream>>>(sBuf, H2, Wws16, H2, sWB, MDU_, nullptr, BT, MDU_, H2, 0);
    z_k<<<cgrid(BT * SS), dim3(256), 0, stream>>>(cWhB, cWuB, WvF, zB);
    zhat_k<<<cgrid(BT), dim3(256), 0, stream>>>(sWB, cWhB, WvF, zhatB);
    attn_mix_k<<<dim3(BT), dim3(64), 0, stream>>>(zB, zhatB, Ub, sBuf, Gb);

    // ---- phase D: layer-2 LSTMs over G -> M (into mMb) ----
    castbf_k<<<cgrid(G4 * G4), dim3(256), 0, stream>>>(Wih[4], 0, W16aD, G4 * G4, flagB);
    castbf_k<<<cgrid(G4 * G4), dim3(256), 0, stream>>>(Wih[5], 0, W16bD, G4 * G4, flagB);
    gemm_bt<<<dim3(8, 32), dim3(256), 0, stream>>>(Gb, G4, W16aD, G4, mxWf, G4, bsum[4], BT, G4, G4, 1);
    gemm_bt<<<dim3(8, 32), dim3(256), 0, stream>>>(Gb, G4, W16bD, G4, mxWb, G4, bsum[5], BT, G4, G4, 1);
    lstm_coop<<<dim3(4, 2, 1), dim3(256), 0, stream>>>(
        mxWf, mxWb, WF[4], WF[5], TT,
        mMb, H2, (u16*)nullptr, 0, (const int*)nullptr, 1, 0, 0, hx32, cnts, 66);

    // ---- output ----
    logit_k<<<dim3(BT / 4), dim3(256), 0, stream>>>(Gb, mMb, Wout16, boutF, d_out, flagB);
}